// Round 10
// baseline (54.689 us; speedup 1.0000x reference)
//
#include <hip/hip_runtime.h>
#include <hip/hip_bf16.h>

#define DIN  1024
#define DOUT 1024
#define MROWS 8192   // B*S = 4*2048

#define BM 128
#define BN 128
#define BK 64
#define NKT (DIN / BK)   // 16 K-tiles

typedef __attribute__((ext_vector_type(8))) short short8;
typedef __attribute__((ext_vector_type(4))) float f32x4;

__device__ __forceinline__ ushort f2bf(float f) {
    union { float f; unsigned u; } x; x.f = f;
    unsigned u = x.u + 0x7fffu + ((x.u >> 16) & 1u);  // RNE
    return (ushort)(u >> 16);
}

// ---------- pass 1 (fused): X f32->bf16 cvt  +  Wv [K][N] -> WvT [N][K] bf16 ----------
__global__ void prep_kernel(const float* __restrict__ X, ushort* __restrict__ Xb,
                            const float* __restrict__ W, ushort* __restrict__ Wt) {
    __shared__ float tile[32][33];
    const int b = blockIdx.x;
    if (b < 2048) {
        const float4* X4 = (const float4*)X;
        ushort4* O4 = (ushort4*)Xb;
        const int n4 = MROWS * DIN / 4;
        for (int idx = b * 256 + threadIdx.x; idx < n4; idx += 2048 * 256) {
            float4 v = X4[idx];
            ushort4 o;
            o.x = f2bf(v.x); o.y = f2bf(v.y); o.z = f2bf(v.z); o.w = f2bf(v.w);
            O4[idx] = o;
        }
    } else {
        const int t = b - 2048;            // 0..1023
        const int bx = (t & 31) * 32;      // n base
        const int by = (t >> 5) * 32;      // k base
        const int tx = threadIdx.x & 31;
        const int ty = threadIdx.x >> 5;   // 0..7
#pragma unroll
        for (int i = 0; i < 32; i += 8)
            tile[ty + i][tx] = W[(size_t)(by + ty + i) * DOUT + (bx + tx)];
        __syncthreads();
#pragma unroll
        for (int i = 0; i < 32; i += 8)
            Wt[(size_t)(bx + ty + i) * DIN + (by + tx)] = f2bf(tile[tx][ty + i]);
    }
}

// ---------- pass 2: C[M][N] = Xb[M][K] @ WvT[N][K]^T + bias ----------
// B-IN-REGISTERS: B panel (2MB, L2-hot) is loaded global->reg once per
// 2-K-tile pass (16 b128/wave, amortized over ~2500 cyc of MFMA); LDS holds
// A ONLY (32 KB double-buffered) -> LDS-pipe/tile halves vs R2 and MFMA
// becomes the dominant pipe (1242 vs 768 cyc/CU/tile). 128x128 tile,
// 4 waves (64x64 each), grid 512 = 2 INDEPENDENT blocks/CU (own barriers).
// A staging via global_load_lds w16 + source-XOR swizzle (rule #21), plain
// __syncthreads per tile. Epilogue/frag math identical to the verified R2.
__global__ __launch_bounds__(256, 2) void gemm_bias(
    const ushort* __restrict__ Xb,    // [8192][1024] bf16
    const ushort* __restrict__ Wt,    // [1024 n][1024 k] bf16
    const float* __restrict__ bias,   // [1024]
    float* __restrict__ out)          // [8192][1024] f32
{
    __shared__ ushort As[2][BM * BK];   // 2 x 16 KiB = 32 KiB

    const int tid  = threadIdx.x;
    const int lane = tid & 63;
    const int wid  = tid >> 6;     // 0..3
    const int wr   = wid >> 1;     // 0..1  (wave M slab, 64 rows)
    const int wc   = wid & 1;      // 0..1  (wave N slab, 64 cols)
    const int g    = lane >> 4;    // 0..3

    // XCD-aware bijective swizzle: 512 blocks = 8 XCDs x 64 (n fastest).
    const int bid = blockIdx.x;
    const int swz = (bid & 7) * 64 + (bid >> 3);
    const int bm = (swz >> 3) * BM;
    const int bn = (swz & 7) * BN;

    // Stage A K-tile kt into buffer b: 4 gload_lds w16/thread, LINEAR dest,
    // T2 via XOR-permuted global source chunk (both-sides involution).
    auto stageA = [&](int b, int kt) {
#pragma unroll
        for (int i = 0; i < 4; ++i) {
            const int c   = i * 256 + tid;      // chunk 0..1023
            const int rl  = c >> 3;             // row 0..127
            const int scc = (c & 7) ^ (rl & 7); // swizzled source slot
            __builtin_amdgcn_global_load_lds(
                (const __attribute__((address_space(1))) void*)(Xb + (size_t)(bm + rl) * DIN + kt * BK + scc * 8),
                (__attribute__((address_space(3))) void*)(&As[b][(i * 256 + wid * 64) * 8]),
                16, 0, 0);
        }
    };

    f32x4 acc[4][4];
#pragma unroll
    for (int i = 0; i < 4; ++i)
#pragma unroll
        for (int j = 0; j < 4; ++j)
            acc[i][j] = (f32x4){0.f, 0.f, 0.f, 0.f};

    const int am = wr * 64 + (lane & 15);
    // B fragment source: row = bn + wc*64 + j*16 + (lane&15), k-slice g*8.
    const ushort* bSrc = Wt + (size_t)(bn + wc * 64 + (lane & 15)) * DIN + g * 8;

    // ---- prologue ----
    stageA(0, 0);
    __syncthreads();

    short8 bf[4][4];   // B frags for one 2-tile pass: [kh 0..3][j 0..3], static idx

    // ---- main: 8 passes x 2 K-tiles. Load pass's B regs once, then per
    // tile: stage A(t+1) | 8 ds_read_b128 | 32 MFMA | __syncthreads. ----
#pragma unroll 1
    for (int p = 0; p < 8; ++p) {
#pragma unroll
        for (int kh = 0; kh < 4; ++kh)
#pragma unroll
            for (int j = 0; j < 4; ++j)
                bf[kh][j] = *(const short8*)(bSrc + (size_t)j * 16 * DIN + p * 128 + kh * 32);
#pragma unroll
        for (int tt = 0; tt < 2; ++tt) {
            const int t   = 2 * p + tt;
            const int buf = t & 1;
            if (t < NKT - 1) stageA(buf ^ 1, t + 1);
#pragma unroll
            for (int ks = 0; ks < 2; ++ks) {
                short8 af[4];
                const int sc = ((ks * 4 + g) ^ (lane & 7)) * 8;
#pragma unroll
                for (int i = 0; i < 4; ++i)
                    af[i] = *(const short8*)(&As[buf][(am + i * 16) * BK + sc]);
#pragma unroll
                for (int i = 0; i < 4; ++i)
#pragma unroll
                    for (int j = 0; j < 4; ++j)
                        acc[i][j] = __builtin_amdgcn_mfma_f32_16x16x32_bf16(af[i], bf[tt * 2 + ks][j], acc[i][j], 0, 0, 0);
            }
            __syncthreads();
        }
    }

    // ---- epilogue: bias + store. C/D: col = lane&15, row = (lane>>4)*4 + r ----
    const int crow = bm + wr * 64 + (lane >> 4) * 4;
    const int ccol = bn + wc * 64 + (lane & 15);
#pragma unroll
    for (int j = 0; j < 4; ++j) {
        const int col = ccol + j * 16;
        const float bval = bias[col];
#pragma unroll
        for (int i = 0; i < 4; ++i) {
#pragma unroll
            for (int r = 0; r < 4; ++r)
                out[(size_t)(crow + i * 16 + r) * DOUT + col] = acc[i][j][r] + bval;
        }
    }
}

// ---------- fallback (only if workspace too small): naive f32 ----------
__global__ void gemm_naive(const float* __restrict__ X, const float* __restrict__ W,
                           const float* __restrict__ b, float* __restrict__ out) {
    int n = blockIdx.x * blockDim.x + threadIdx.x;
    int m = blockIdx.y;
    float acc = b[n];
    for (int k = 0; k < DIN; ++k)
        acc += X[(size_t)m * DIN + k] * W[(size_t)k * DOUT + n];
    out[(size_t)m * DOUT + n] = acc;
}

extern "C" void kernel_launch(void* const* d_in, const int* in_sizes, int n_in,
                              void* d_out, int out_size, void* d_ws, size_t ws_size,
                              hipStream_t stream) {
    // setup_inputs order: X, Wq, bq, Wk, bk, Wv, bv
    const float* X  = (const float*)d_in[0];
    const float* Wv = (const float*)d_in[5];
    const float* bv = (const float*)d_in[6];
    float* out = (float*)d_out;

    const size_t xb_elems = (size_t)MROWS * DIN;
    const size_t wt_elems = (size_t)DOUT * DIN;
    const size_t needed = (xb_elems + wt_elems) * sizeof(ushort);

    if (ws_size < needed) {
        dim3 g(DOUT / 256, MROWS);
        gemm_naive<<<g, 256, 0, stream>>>(X, Wv, bv, out);
        return;
    }

    ushort* Xb = (ushort*)d_ws;
    ushort* Wt = Xb + xb_elems;

    prep_kernel<<<2048 + 1024, 256, 0, stream>>>(X, Xb, Wv, Wt);
    gemm_bias<<<512, 256, 0, stream>>>(Xb, Wt, bv, out);
}